// Round 12
// baseline (161.786 us; speedup 1.0000x reference)
//
#include <hip/hip_runtime.h>
#include <hip/hip_bf16.h>

// GAT layer: N=4096, F_IN=128, F_OUT=64, HEADS=4.
// R23: every intra-chunk opt (R15/R17/R19/R22) was neutral -> the binding
// constraint is the per-chunk vmcnt(0) drain at __syncthreads (the "2-phase
// stall"). Apply the counted-vmcnt pattern (T3/T4): 32 chunks x 128 cols,
// TRIPLE-buffered LDS, one raw s_barrier per chunk preceded by
// s_waitcnt vmcnt(K) with K = own next-chunk DMAs (never 0 in the loop) ->
// chunk ch+2's DMAs stay in flight across the barrier and land under TWO
// compute phases. Rotation safety: DMA(ch+2) targets buf[(ch+2)%3], last
// read at iter ch-1, separated from the issue by barrier_ch; data-ready =
// own vmcnt + barrier. Aux (bits/ed/ed2) joins the DMA stream (waves 3/4/5,
// half-wave). LDS 52.5 KB -> 3 blocks/CU = 24 waves/CU (was 16).
// Compute + epilogue verbatim R19 (same accumulation order).
// Kernels: pack_bits -> gat_prep -> gat_main (fused) -> gat_fin (tiny).

#define NN 4096
#define FIN 128
#define FOUT 64
#define NH 4

typedef __attribute__((ext_vector_type(8))) short bf16x8;
typedef __attribute__((ext_vector_type(4))) float f32x4;
typedef __attribute__((ext_vector_type(4))) unsigned int u32x4;

__device__ __forceinline__ unsigned short f32_bf16(float f) {
    unsigned u = __builtin_bit_cast(unsigned, f);
    u += 0x7fffu + ((u >> 16) & 1u);          // round-to-nearest-even
    return (unsigned short)(u >> 16);
}

__device__ __forceinline__ void gload16(const void* g, void* l) {
    __builtin_amdgcn_global_load_lds(
        (const __attribute__((address_space(1))) unsigned*)g,
        (__attribute__((address_space(3))) unsigned*)l, 16, 0, 0);
}

// ---------------- Kernel 0: pack A (int32 0/1) into bitmask ----------------
__global__ __launch_bounds__(256) void pack_bits(
    const int* __restrict__ A, unsigned long long* __restrict__ Abits)
{
    const int row  = blockIdx.x;
    const int lane = threadIdx.x & 63;
    const int wv   = threadIdx.x >> 6;
    const int* arow = A + (size_t)row * NN;
    #pragma unroll 4
    for (int c = 0; c < 16; ++c) {
        const int col = c * 256 + wv * 64 + lane;
        unsigned long long m = __ballot(__builtin_nontemporal_load(&arow[col]) > 0);
        if (lane == 0) Abits[(size_t)row * 64 + c * 4 + wv] = m;
    }
}

// ---------------- Kernel 1: prep ----------------
__global__ __launch_bounds__(256) void gat_prep(
    const float* __restrict__ X, const float* __restrict__ W,
    const float* __restrict__ b, const float* __restrict__ att,
    unsigned short* __restrict__ HbfT, float* __restrict__ Hrow,
    float* __restrict__ s_out, float* __restrict__ d_out,
    float* __restrict__ es_g, float* __restrict__ es2_g,
    float* __restrict__ ed_g, float* __restrict__ ed2_g)
{
    const int rb = blockIdx.x;           // 0..127
    const int h  = blockIdx.y;           // 0..3
    const int n0 = rb * 32;
    const int t  = threadIdx.x;          // 0..255

    __shared__ float Xl[32][132];
    __shared__ float Wt[128][68];

    for (int g = t; g < 32 * 32; g += 256) {
        int row = g >> 5, c4 = g & 31;
        float4 v = *(const float4*)&X[(size_t)(n0 + row) * FIN + c4 * 4];
        *(float4*)&Xl[row][c4 * 4] = v;
    }
    for (int g = t; g < 64 * 32; g += 256) {
        int o = g >> 5, c4 = g & 31;
        float4 v = *(const float4*)&W[((size_t)h * FOUT + o) * FIN + c4 * 4];
        Wt[c4 * 4 + 0][o] = v.x; Wt[c4 * 4 + 1][o] = v.y;
        Wt[c4 * 4 + 2][o] = v.z; Wt[c4 * 4 + 3][o] = v.w;
    }
    __syncthreads();

    const int rg = t >> 4;               // rows rg*2 .. rg*2+1
    const int og = t & 15;               // cols og*4 .. og*4+3
    float acc[2][4] = {};

    #pragma unroll 4
    for (int f4 = 0; f4 < 32; ++f4) {
        float xv[2][4], wv[4][4];
        #pragma unroll
        for (int i = 0; i < 2; ++i) {
            float4 tmp = *(const float4*)&Xl[rg * 2 + i][f4 * 4];
            xv[i][0] = tmp.x; xv[i][1] = tmp.y; xv[i][2] = tmp.z; xv[i][3] = tmp.w;
        }
        #pragma unroll
        for (int k = 0; k < 4; ++k) {
            float4 tmp = *(const float4*)&Wt[f4 * 4 + k][og * 4];
            wv[k][0] = tmp.x; wv[k][1] = tmp.y; wv[k][2] = tmp.z; wv[k][3] = tmp.w;
        }
        #pragma unroll
        for (int i = 0; i < 2; ++i)
            #pragma unroll
            for (int k = 0; k < 4; ++k)
                #pragma unroll
                for (int jj = 0; jj < 4; ++jj)
                    acc[i][jj] = fmaf(xv[i][k], wv[k][jj], acc[i][jj]);
    }

    float bb[4], as_[4], ad_[4];
    #pragma unroll
    for (int jj = 0; jj < 4; ++jj) {
        bb[jj]  = b[h * FOUT + og * 4 + jj];
        as_[jj] = att[h * 2 * FOUT + og * 4 + jj];
        ad_[jj] = att[h * 2 * FOUT + FOUT + og * 4 + jj];
    }
    #pragma unroll
    for (int i = 0; i < 2; ++i)
        #pragma unroll
        for (int jj = 0; jj < 4; ++jj)
            acc[i][jj] += bb[jj];

    float sp[2] = {0.f, 0.f}, dp[2] = {0.f, 0.f};
    #pragma unroll
    for (int i = 0; i < 2; ++i)
        #pragma unroll
        for (int jj = 0; jj < 4; ++jj) {
            sp[i] = fmaf(acc[i][jj], as_[jj], sp[i]);
            dp[i] = fmaf(acc[i][jj], ad_[jj], dp[i]);
        }
    #pragma unroll
    for (int off = 1; off < 16; off <<= 1) {
        #pragma unroll
        for (int i = 0; i < 2; ++i) {
            sp[i] += __shfl_xor(sp[i], off);
            dp[i] += __shfl_xor(dp[i], off);
        }
    }
    if (og == 0) {
        #pragma unroll
        for (int i = 0; i < 2; ++i) {
            int nn = n0 + rg * 2 + i;
            s_out[h * NN + nn]  = sp[i];
            d_out[h * NN + nn]  = dp[i];
            es_g [h * NN + nn]  = __expf(sp[i]);
            es2_g[h * NN + nn]  = __expf(0.01f * sp[i]);
            ed_g [h * NN + nn]  = __expf(dp[i]);
            ed2_g[h * NN + nn]  = __expf(0.01f * dp[i]);
        }
    }

    #pragma unroll
    for (int i = 0; i < 2; ++i) {
        float4 v = make_float4(acc[i][0], acc[i][1], acc[i][2], acc[i][3]);
        *(float4*)&Hrow[((size_t)h * NN + n0 + rg * 2 + i) * FOUT + og * 4] = v;
    }
    #pragma unroll
    for (int jj = 0; jj < 4; ++jj) {
        int o = og * 4 + jj;
        ushort2 p;
        p.x = f32_bf16(acc[0][jj]);
        p.y = f32_bf16(acc[1][jj]);
        *(ushort2*)&HbfT[((size_t)h * FOUT + o) * NN + n0 + rg * 2] = p;
    }
}

// ---------------- Kernel 2: fused masked softmax-aggregate ------------------
// Grid 512 x 512thr. id -> h = id&3, tile = id>>2 (32 rows). 8 waves:
// rg = w&1 (16 rows), kg = w>>1 (32-col group of each 128-col chunk).
// 32 chunks, TRIPLE-buffered LDS, counted-vmcnt + raw barrier per chunk.
// Epilogue: LDS K-reduction (aliases H), fused normalize + diag + store.
struct SMem {
    union {
        __align__(16) unsigned short H[3][64][128];  // 48 KB (3 bufs)
        struct {
            float red[6][16][68];                    // 25.5 KB (pad 68)
            float redl[6][16];
        } fin;
    };
    unsigned bits[3][32][4];                         // 1.5 KB
    float ed [3][128];                               // 1.5 KB
    float ed2[3][128];                               // 1.5 KB
};

__global__ __launch_bounds__(512, 4) void gat_main(
    const unsigned* __restrict__ Abits, const unsigned short* __restrict__ HbfT,
    const float* __restrict__ s_g, const float* __restrict__ d_g,
    const float* __restrict__ es_g, const float* __restrict__ es2_g,
    const float* __restrict__ ed_g, const float* __restrict__ ed2_g,
    const float* __restrict__ Hrow, float* __restrict__ outH)
{
    const int id   = blockIdx.x;         // 0..511
    const int h    = id & 3;
    const int tile = id >> 2;            // 0..127
    const int n0   = tile * 32;
    const int tid  = threadIdx.x;        // 0..511
    const int w    = tid >> 6;           // wave 0..7
    const int lane = tid & 63;
    const int r    = lane & 15;          // A row within 16-row group / C col
    const int q    = lane >> 4;          // quad
    const int qs   = q * 8;
    const int rg   = w & 1;              // row group
    const int kg   = w >> 1;             // 32-col group 0..3

    __shared__ SMem sm;                  // 52.5 KB -> 3 blocks/CU

    const int nrow = n0 + rg * 16 + r;
    const float es  = es_g [h * NN + nrow];
    const float es2 = es2_g[h * NN + nrow];

    // swizzled 16B-block index for B-fragment reads (constant per thread)
    const int sblk = ((kg * 4 + q) ^ r) & 15;

    // ---- DMA sources (H pre-swizzled; aux linear) ----
    // H: wave w stages rows [8w, 8w+8) via 2 DMAs of 4 rows each.
    const int rowA = 8 * w + (lane >> 4);            // DMA0: rows 8w..8w+3
    const int rowB = rowA + 4;                       // DMA1: rows 8w+4..8w+7
    const int blkL = lane & 15;                      // linear dest 16B block
    const unsigned short* gH0 =
        HbfT + ((size_t)(h * FOUT) + rowA) * NN + (size_t)(blkL ^ (rowA & 15)) * 8;
    const unsigned short* gH1 =
        HbfT + ((size_t)(h * FOUT) + rowB) * NN + (size_t)(blkL ^ (rowB & 15)) * 8;
    // aux (half-wave DMAs): w3 bits, w4 ed, w5 ed2
    const unsigned* gBits = Abits + (size_t)(n0 + lane) * 128;   // + ch*4
    const float*    gEd   = ed_g  + (size_t)h * NN + lane * 4;   // + ch*128
    const float*    gEd2  = ed2_g + (size_t)h * NN + lane * 4;

    bf16x8 ones;
    #pragma unroll
    for (int i = 0; i < 8; ++i) ones[i] = (short)0x3F80;   // bf16 1.0

    f32x4 acc0 = {0,0,0,0}, acc1 = {0,0,0,0}, acc2 = {0,0,0,0},
          acc3 = {0,0,0,0}, accl = {0,0,0,0};

    // stage chunk chn into buffer bt
    auto STAGE = [&](int chn, int bt) {
        const size_t coff = (size_t)chn * 128;
        gload16(gH0 + coff, &sm.H[bt][8 * w][0]);
        gload16(gH1 + coff, &sm.H[bt][8 * w + 4][0]);
        if      (w == 3) { if (lane < 32) gload16(gBits + (size_t)chn * 4, &sm.bits[bt][0][0]); }
        else if (w == 4) { if (lane < 32) gload16(gEd   + coff,            &sm.ed [bt][0]); }
        else if (w == 5) { if (lane < 32) gload16(gEd2  + coff,            &sm.ed2[bt][0]); }
    };

    // compute chunk from buffer bc
    auto COMPUTE = [&](int bc) {
        const unsigned bits8 = sm.bits[bc][rg * 16 + r][kg] >> qs;
        const float4 e0 = *(const float4*)&sm.ed [bc][kg * 32 + qs];
        const float4 e1 = *(const float4*)&sm.ed [bc][kg * 32 + qs + 4];
        const float4 g0 = *(const float4*)&sm.ed2[bc][kg * 32 + qs];
        const float4 g1 = *(const float4*)&sm.ed2[bc][kg * 32 + qs + 4];
        const float edv [8] = {e0.x, e0.y, e0.z, e0.w, e1.x, e1.y, e1.z, e1.w};
        const float ed2v[8] = {g0.x, g0.y, g0.z, g0.w, g1.x, g1.y, g1.z, g1.w};
        u32x4 afu;
        #pragma unroll
        for (int p = 0; p < 4; ++p) {
            const int j0 = 2 * p, j1 = 2 * p + 1;
            float wa = (bits8 & (1u << j0))
                     ? fmaxf(es * edv[j0], es2 * ed2v[j0]) : 0.0f;
            float wb = (bits8 & (1u << j1))
                     ? fmaxf(es * edv[j1], es2 * ed2v[j1]) : 0.0f;
            __hip_bfloat162 pk = __float22bfloat162_rn(make_float2(wa, wb));
            unsigned u;
            __builtin_memcpy(&u, &pk, sizeof(u));   // v_cvt_pk path
            afu[p] = u;
        }
        const bf16x8 af = __builtin_bit_cast(bf16x8, afu);

        const bf16x8 b0 = *(const bf16x8*)&sm.H[bc][r     ][sblk * 8];
        const bf16x8 b1 = *(const bf16x8*)&sm.H[bc][r + 16][sblk * 8];
        const bf16x8 b2 = *(const bf16x8*)&sm.H[bc][r + 32][sblk * 8];
        const bf16x8 b3 = *(const bf16x8*)&sm.H[bc][r + 48][sblk * 8];

        acc0 = __builtin_amdgcn_mfma_f32_16x16x32_bf16(af, b0,   acc0, 0, 0, 0);
        acc1 = __builtin_amdgcn_mfma_f32_16x16x32_bf16(af, b1,   acc1, 0, 0, 0);
        acc2 = __builtin_amdgcn_mfma_f32_16x16x32_bf16(af, b2,   acc2, 0, 0, 0);
        acc3 = __builtin_amdgcn_mfma_f32_16x16x32_bf16(af, b3,   acc3, 0, 0, 0);
        accl = __builtin_amdgcn_mfma_f32_16x16x32_bf16(af, ones, accl, 0, 0, 0);
    };

    // ---- prologue: chunk0 -> buf0, chunk1 -> buf1 ----
    STAGE(0, 0);
    STAGE(1, 1);

    int bc = 0;
    for (int ch = 0; ch < 31; ++ch) {
        // counted wait: own chunk-ch DMAs done; chunk-ch+1's stay in flight
        if (w >= 3 && w <= 5) asm volatile("s_waitcnt vmcnt(3)" ::: "memory");
        else                  asm volatile("s_waitcnt vmcnt(2)" ::: "memory");
        __builtin_amdgcn_s_barrier();    // all waves' chunk-ch data in LDS
        if (ch + 2 < 32) {
            int bt = bc + 2; if (bt >= 3) bt -= 3;
            STAGE(ch + 2, bt);           // lands under TWO compute phases
        }
        COMPUTE(bc);
        bc = (bc == 2) ? 0 : bc + 1;
    }
    // peeled last chunk: full drain
    asm volatile("s_waitcnt vmcnt(0)" ::: "memory");
    __builtin_amdgcn_s_barrier();
    COMPUTE(bc);

    __syncthreads();                     // before LDS union reuse

    // ---- K-partial reduction: kg 1..3 dump to LDS, kg 0 accumulates ----
    if (kg > 0) {
        const int widx = (kg - 1) * 2 + rg;
        #pragma unroll
        for (int reg = 0; reg < 4; ++reg) {
            const int rr = q * 4 + reg;
            sm.fin.red[widx][rr][ 0 + r] = acc0[reg];
            sm.fin.red[widx][rr][16 + r] = acc1[reg];
            sm.fin.red[widx][rr][32 + r] = acc2[reg];
            sm.fin.red[widx][rr][48 + r] = acc3[reg];
        }
        if (r == 0) {
            #pragma unroll
            for (int reg = 0; reg < 4; ++reg)
                sm.fin.redl[widx][q * 4 + reg] = accl[reg];
        }
    }
    __syncthreads();
    if (kg == 0) {
        #pragma unroll
        for (int kk = 0; kk < 3; ++kk) {
            const int widx = kk * 2 + rg;
            #pragma unroll
            for (int reg = 0; reg < 4; ++reg) {
                const int rr = q * 4 + reg;
                acc0[reg] += sm.fin.red[widx][rr][ 0 + r];
                acc1[reg] += sm.fin.red[widx][rr][16 + r];
                acc2[reg] += sm.fin.red[widx][rr][32 + r];
                acc3[reg] += sm.fin.red[widx][rr][48 + r];
                accl[reg] += sm.fin.redl[widx][rr];
            }
        }
        // ---- fused normalize + diagonal + store per-head output ----
        #pragma unroll
        for (int reg = 0; reg < 4; ++reg) {
            const int rr  = q * 4 + reg;
            const int nn2 = n0 + rg * 16 + rr;
            const float tt = s_g[h * NN + nn2] + d_g[h * NN + nn2];
            const float wd = __expf(fmaxf(tt, 0.01f * tt));
            const float inv = 0.25f / (accl[reg] + wd);
            const float* hr = &Hrow[((size_t)h * NN + nn2) * FOUT];
            float*       ob = &outH[((size_t)h * NN + nn2) * FOUT];
            ob[ 0 + r] = (acc0[reg] + wd * hr[ 0 + r]) * inv;
            ob[16 + r] = (acc1[reg] + wd * hr[16 + r]) * inv;
            ob[32 + r] = (acc2[reg] + wd * hr[32 + r]) * inv;
            ob[48 + r] = (acc3[reg] + wd * hr[48 + r]) * inv;
        }
    }
}

// ---------------- Kernel 3: tiny finalize — sum 4 heads ----------------
__global__ __launch_bounds__(256) void gat_fin(
    const float* __restrict__ outH, float* __restrict__ out)
{
    const int i = blockIdx.x * 256 + threadIdx.x;    // 0..65535 float4s
    const f32x4* p = (const f32x4*)outH;
    f32x4 v0 = __builtin_nontemporal_load(p + i);
    f32x4 v1 = __builtin_nontemporal_load(p + i +  65536);
    f32x4 v2 = __builtin_nontemporal_load(p + i + 131072);
    f32x4 v3 = __builtin_nontemporal_load(p + i + 196608);
    f32x4 s = (v0 + v1) + (v2 + v3);
    *((f32x4*)out + i) = s;
}

extern "C" void kernel_launch(void* const* d_in, const int* in_sizes, int n_in,
                              void* d_out, int out_size, void* d_ws, size_t ws_size,
                              hipStream_t stream) {
    const float* X   = (const float*)d_in[0];
    const int*   A   = (const int*)  d_in[1];
    const float* W   = (const float*)d_in[2];
    const float* b   = (const float*)d_in[3];
    const float* att = (const float*)d_in[4];
    float* out = (float*)d_out;

    char* ws = (char*)d_ws;
    unsigned short* HbfT = (unsigned short*)ws;                    // 2 MB
    size_t off = (size_t)NH * FOUT * NN * 2;
    float* s_buf   = (float*)(ws + off);  off += (size_t)NH * NN * 4;
    float* d_buf   = (float*)(ws + off);  off += (size_t)NH * NN * 4;
    float* es_buf  = (float*)(ws + off);  off += (size_t)NH * NN * 4;
    float* es2_buf = (float*)(ws + off);  off += (size_t)NH * NN * 4;
    float* ed_buf  = (float*)(ws + off);  off += (size_t)NH * NN * 4;
    float* ed2_buf = (float*)(ws + off);  off += (size_t)NH * NN * 4;
    unsigned long long* Abits = (unsigned long long*)(ws + off);
    off += (size_t)NN * 64 * 8;                                         // 2 MB
    float* Hrow   = (float*)(ws + off);
    off += (size_t)NH * NN * FOUT * 4;                                  // 4 MB
    float* outH   = (float*)(ws + off);
    off += (size_t)NH * NN * FOUT * 4;                                  // 4 MB

    pack_bits<<<NN, 256, 0, stream>>>(A, Abits);
    gat_prep<<<dim3(128, 4), 256, 0, stream>>>(X, W, b, att, HbfT, Hrow,
                                               s_buf, d_buf,
                                               es_buf, es2_buf, ed_buf, ed2_buf);
    gat_main<<<512, 512, 0, stream>>>((const unsigned*)Abits, HbfT,
                                      s_buf, d_buf,
                                      es_buf, es2_buf, ed_buf, ed2_buf,
                                      Hrow, outH);
    gat_fin<<<256, 256, 0, stream>>>(outH, out);
}

// Round 13
// 157.504 us; speedup vs baseline: 1.0272x; 1.0272x over previous
//
#include <hip/hip_runtime.h>
#include <hip/hip_bf16.h>

// GAT layer: N=4096, F_IN=128, F_OUT=64, HEADS=4.
// R24: third-time lesson — occupancy was GRID-capped at 2 blocks/CU every
// round (512 blocks / 256 CUs); R23's LDS shrink + counted vmcnt had nothing
// to overlap. Fix all three constraints at once: (1) grid 1024 via column
// halving (block = head x 32 rows x 2048 cols; H-panel L2 traffic unchanged,
// id%8 -> one (h,half) panel per XCD); (2) 128-col chunks dbuf -> LDS 35 KB
// (4 blocks/CU by LDS); (3) launch_bounds(512,6) -> VGPR cap 85 > ~70 need
// (no spill) -> >=3 blocks/CU = 24+ waves/CU (was 16). Partial outputs
// (Hpart 8MB + lpart) folded into a fused fin (halves+normalize+head-sum).
// Compute body verbatim R23 (verified); loop = R19 simple dbuf (best).
// Kernels: pack_bits -> gat_prep -> gat_main (fused) -> gat_fin.

#define NN 4096
#define FIN 128
#define FOUT 64
#define NH 4

typedef __attribute__((ext_vector_type(8))) short bf16x8;
typedef __attribute__((ext_vector_type(4))) float f32x4;
typedef __attribute__((ext_vector_type(4))) unsigned int u32x4;

__device__ __forceinline__ unsigned short f32_bf16(float f) {
    unsigned u = __builtin_bit_cast(unsigned, f);
    u += 0x7fffu + ((u >> 16) & 1u);          // round-to-nearest-even
    return (unsigned short)(u >> 16);
}

__device__ __forceinline__ void gload16(const void* g, void* l) {
    __builtin_amdgcn_global_load_lds(
        (const __attribute__((address_space(1))) unsigned*)g,
        (__attribute__((address_space(3))) unsigned*)l, 16, 0, 0);
}

// ---------------- Kernel 0: pack A (int32 0/1) into bitmask ----------------
__global__ __launch_bounds__(256) void pack_bits(
    const int* __restrict__ A, unsigned long long* __restrict__ Abits)
{
    const int row  = blockIdx.x;
    const int lane = threadIdx.x & 63;
    const int wv   = threadIdx.x >> 6;
    const int* arow = A + (size_t)row * NN;
    #pragma unroll 4
    for (int c = 0; c < 16; ++c) {
        const int col = c * 256 + wv * 64 + lane;
        unsigned long long m = __ballot(__builtin_nontemporal_load(&arow[col]) > 0);
        if (lane == 0) Abits[(size_t)row * 64 + c * 4 + wv] = m;
    }
}

// ---------------- Kernel 1: prep ----------------
__global__ __launch_bounds__(256) void gat_prep(
    const float* __restrict__ X, const float* __restrict__ W,
    const float* __restrict__ b, const float* __restrict__ att,
    unsigned short* __restrict__ HbfT, float* __restrict__ Hrow,
    float* __restrict__ s_out, float* __restrict__ d_out,
    float* __restrict__ es_g, float* __restrict__ es2_g,
    float* __restrict__ ed_g, float* __restrict__ ed2_g)
{
    const int rb = blockIdx.x;           // 0..127
    const int h  = blockIdx.y;           // 0..3
    const int n0 = rb * 32;
    const int t  = threadIdx.x;          // 0..255

    __shared__ float Xl[32][132];
    __shared__ float Wt[128][68];

    for (int g = t; g < 32 * 32; g += 256) {
        int row = g >> 5, c4 = g & 31;
        float4 v = *(const float4*)&X[(size_t)(n0 + row) * FIN + c4 * 4];
        *(float4*)&Xl[row][c4 * 4] = v;
    }
    for (int g = t; g < 64 * 32; g += 256) {
        int o = g >> 5, c4 = g & 31;
        float4 v = *(const float4*)&W[((size_t)h * FOUT + o) * FIN + c4 * 4];
        Wt[c4 * 4 + 0][o] = v.x; Wt[c4 * 4 + 1][o] = v.y;
        Wt[c4 * 4 + 2][o] = v.z; Wt[c4 * 4 + 3][o] = v.w;
    }
    __syncthreads();

    const int rg = t >> 4;               // rows rg*2 .. rg*2+1
    const int og = t & 15;               // cols og*4 .. og*4+3
    float acc[2][4] = {};

    #pragma unroll 4
    for (int f4 = 0; f4 < 32; ++f4) {
        float xv[2][4], wv[4][4];
        #pragma unroll
        for (int i = 0; i < 2; ++i) {
            float4 tmp = *(const float4*)&Xl[rg * 2 + i][f4 * 4];
            xv[i][0] = tmp.x; xv[i][1] = tmp.y; xv[i][2] = tmp.z; xv[i][3] = tmp.w;
        }
        #pragma unroll
        for (int k = 0; k < 4; ++k) {
            float4 tmp = *(const float4*)&Wt[f4 * 4 + k][og * 4];
            wv[k][0] = tmp.x; wv[k][1] = tmp.y; wv[k][2] = tmp.z; wv[k][3] = tmp.w;
        }
        #pragma unroll
        for (int i = 0; i < 2; ++i)
            #pragma unroll
            for (int k = 0; k < 4; ++k)
                #pragma unroll
                for (int jj = 0; jj < 4; ++jj)
                    acc[i][jj] = fmaf(xv[i][k], wv[k][jj], acc[i][jj]);
    }

    float bb[4], as_[4], ad_[4];
    #pragma unroll
    for (int jj = 0; jj < 4; ++jj) {
        bb[jj]  = b[h * FOUT + og * 4 + jj];
        as_[jj] = att[h * 2 * FOUT + og * 4 + jj];
        ad_[jj] = att[h * 2 * FOUT + FOUT + og * 4 + jj];
    }
    #pragma unroll
    for (int i = 0; i < 2; ++i)
        #pragma unroll
        for (int jj = 0; jj < 4; ++jj)
            acc[i][jj] += bb[jj];

    float sp[2] = {0.f, 0.f}, dp[2] = {0.f, 0.f};
    #pragma unroll
    for (int i = 0; i < 2; ++i)
        #pragma unroll
        for (int jj = 0; jj < 4; ++jj) {
            sp[i] = fmaf(acc[i][jj], as_[jj], sp[i]);
            dp[i] = fmaf(acc[i][jj], ad_[jj], dp[i]);
        }
    #pragma unroll
    for (int off = 1; off < 16; off <<= 1) {
        #pragma unroll
        for (int i = 0; i < 2; ++i) {
            sp[i] += __shfl_xor(sp[i], off);
            dp[i] += __shfl_xor(dp[i], off);
        }
    }
    if (og == 0) {
        #pragma unroll
        for (int i = 0; i < 2; ++i) {
            int nn = n0 + rg * 2 + i;
            s_out[h * NN + nn]  = sp[i];
            d_out[h * NN + nn]  = dp[i];
            es_g [h * NN + nn]  = __expf(sp[i]);
            es2_g[h * NN + nn]  = __expf(0.01f * sp[i]);
            ed_g [h * NN + nn]  = __expf(dp[i]);
            ed2_g[h * NN + nn]  = __expf(0.01f * dp[i]);
        }
    }

    #pragma unroll
    for (int i = 0; i < 2; ++i) {
        float4 v = make_float4(acc[i][0], acc[i][1], acc[i][2], acc[i][3]);
        *(float4*)&Hrow[((size_t)h * NN + n0 + rg * 2 + i) * FOUT + og * 4] = v;
    }
    #pragma unroll
    for (int jj = 0; jj < 4; ++jj) {
        int o = og * 4 + jj;
        ushort2 p;
        p.x = f32_bf16(acc[0][jj]);
        p.y = f32_bf16(acc[1][jj]);
        *(ushort2*)&HbfT[((size_t)h * FOUT + o) * NN + n0 + rg * 2] = p;
    }
}

// ---------------- Kernel 2: fused masked softmax-aggregate ------------------
// Grid 1024 x 512thr. id: h = id&3, half = (id>>2)&1, tile = id>>3.
// Block = head h, rows [tile*32,+32), cols [half*2048,+2048). id%8 fixes
// (h,half) per XCD (one 256 KB panel per XCD L2). 8 waves: rg=w&1 (16 rows),
// kg=w>>1 (32-col group of each 128-col chunk). 16 chunks, dbuf LDS (35 KB
// -> up to 4 blocks/CU), all staging via global_load_lds. Epilogue: 4-way
// kg-reduction in LDS (aliases H), write partial Hpart/lpart (no normalize).
struct SMem {
    union {
        __align__(16) unsigned short H[2][64][128];  // 32 KB dbuf
        struct {
            float red[6][16][68];                    // 25.5 KB (pad 68)
            float redl[6][16];
        } fin;
    };
    unsigned bits[2][32][4];                         // 1 KB
    float ed [2][128];                               // 1 KB
    float ed2[2][128];                               // 1 KB
};

__global__ __launch_bounds__(512, 6) void gat_main(
    const unsigned* __restrict__ Abits, const unsigned short* __restrict__ HbfT,
    const float* __restrict__ es_g, const float* __restrict__ es2_g,
    const float* __restrict__ ed_g, const float* __restrict__ ed2_g,
    float* __restrict__ Hpart, float* __restrict__ lpart)
{
    const int id   = blockIdx.x;         // 0..1023
    const int h    = id & 3;
    const int half = (id >> 2) & 1;
    const int tile = id >> 3;            // 0..127
    const int n0   = tile * 32;
    const int c0   = half * 2048;
    const int tid  = threadIdx.x;        // 0..511
    const int w    = tid >> 6;           // wave 0..7
    const int lane = tid & 63;
    const int r    = lane & 15;          // A row within 16-row group / C col
    const int q    = lane >> 4;          // quad
    const int qs   = q * 8;
    const int rg   = w & 1;              // row group
    const int kg   = w >> 1;             // 32-col group 0..3

    __shared__ SMem sm;                  // 35 KB

    const int nrow = n0 + rg * 16 + r;
    const float es  = es_g [h * NN + nrow];
    const float es2 = es2_g[h * NN + nrow];

    // swizzled 16B-block index for B-fragment reads (constant per thread)
    const int sblk = ((kg * 4 + q) ^ r) & 15;

    // ---- DMA sources (H pre-swizzled; aux linear) ----
    // H: wave w stages rows [8w, 8w+8) via 2 DMAs of 4 rows each.
    const int rowA = 8 * w + (lane >> 4);            // DMA0: rows 8w..8w+3
    const int rowB = rowA + 4;                       // DMA1: rows 8w+4..8w+7
    const int blkL = lane & 15;                      // linear dest 16B block
    const unsigned short* gH0 =
        HbfT + ((size_t)(h * FOUT) + rowA) * NN + c0 + (size_t)(blkL ^ (rowA & 15)) * 8;
    const unsigned short* gH1 =
        HbfT + ((size_t)(h * FOUT) + rowB) * NN + c0 + (size_t)(blkL ^ (rowB & 15)) * 8;
    // aux (half-wave DMAs): w3 bits, w4 ed, w5 ed2
    const unsigned* gBits = Abits + (size_t)(n0 + lane) * 128 + half * 64;  // + ch*4
    const float*    gEd   = ed_g  + (size_t)h * NN + c0 + lane * 4;         // + ch*128
    const float*    gEd2  = ed2_g + (size_t)h * NN + c0 + lane * 4;

    bf16x8 ones;
    #pragma unroll
    for (int i = 0; i < 8; ++i) ones[i] = (short)0x3F80;   // bf16 1.0

    f32x4 acc0 = {0,0,0,0}, acc1 = {0,0,0,0}, acc2 = {0,0,0,0},
          acc3 = {0,0,0,0}, accl = {0,0,0,0};

    auto STAGE = [&](int chn, int bt) {
        const size_t coff = (size_t)chn * 128;
        gload16(gH0 + coff, &sm.H[bt][8 * w][0]);
        gload16(gH1 + coff, &sm.H[bt][8 * w + 4][0]);
        if      (w == 3) { if (lane < 32) gload16(gBits + (size_t)chn * 4, &sm.bits[bt][0][0]); }
        else if (w == 4) { if (lane < 32) gload16(gEd  + coff, &sm.ed [bt][0]); }
        else if (w == 5) { if (lane < 32) gload16(gEd2 + coff, &sm.ed2[bt][0]); }
    };

    auto COMPUTE = [&](int bc) {
        const unsigned bits8 = sm.bits[bc][rg * 16 + r][kg] >> qs;
        const float4 e0 = *(const float4*)&sm.ed [bc][kg * 32 + qs];
        const float4 e1 = *(const float4*)&sm.ed [bc][kg * 32 + qs + 4];
        const float4 g0 = *(const float4*)&sm.ed2[bc][kg * 32 + qs];
        const float4 g1 = *(const float4*)&sm.ed2[bc][kg * 32 + qs + 4];
        const float edv [8] = {e0.x, e0.y, e0.z, e0.w, e1.x, e1.y, e1.z, e1.w};
        const float ed2v[8] = {g0.x, g0.y, g0.z, g0.w, g1.x, g1.y, g1.z, g1.w};
        u32x4 afu;
        #pragma unroll
        for (int p = 0; p < 4; ++p) {
            const int j0 = 2 * p, j1 = 2 * p + 1;
            float wa = (bits8 & (1u << j0))
                     ? fmaxf(es * edv[j0], es2 * ed2v[j0]) : 0.0f;
            float wb = (bits8 & (1u << j1))
                     ? fmaxf(es * edv[j1], es2 * ed2v[j1]) : 0.0f;
            __hip_bfloat162 pk = __float22bfloat162_rn(make_float2(wa, wb));
            unsigned u;
            __builtin_memcpy(&u, &pk, sizeof(u));   // v_cvt_pk path
            afu[p] = u;
        }
        const bf16x8 af = __builtin_bit_cast(bf16x8, afu);

        const bf16x8 b0 = *(const bf16x8*)&sm.H[bc][r     ][sblk * 8];
        const bf16x8 b1 = *(const bf16x8*)&sm.H[bc][r + 16][sblk * 8];
        const bf16x8 b2 = *(const bf16x8*)&sm.H[bc][r + 32][sblk * 8];
        const bf16x8 b3 = *(const bf16x8*)&sm.H[bc][r + 48][sblk * 8];

        acc0 = __builtin_amdgcn_mfma_f32_16x16x32_bf16(af, b0,   acc0, 0, 0, 0);
        acc1 = __builtin_amdgcn_mfma_f32_16x16x32_bf16(af, b1,   acc1, 0, 0, 0);
        acc2 = __builtin_amdgcn_mfma_f32_16x16x32_bf16(af, b2,   acc2, 0, 0, 0);
        acc3 = __builtin_amdgcn_mfma_f32_16x16x32_bf16(af, b3,   acc3, 0, 0, 0);
        accl = __builtin_amdgcn_mfma_f32_16x16x32_bf16(af, ones, accl, 0, 0, 0);
    };

    // ---- prologue: stage chunk 0 into buffer 0 ----
    STAGE(0, 0);
    __syncthreads();                     // vmcnt(0) drain + barrier

    for (int ch = 0; ch < 16; ++ch) {
        const int buf = ch & 1;
        if (ch < 15) STAGE(ch + 1, buf ^ 1);   // lands during this compute
        COMPUTE(buf);
        __syncthreads();                 // drains next-chunk DMA + barrier
    }

    // ---- kg-reduction: kg 1..3 dump to LDS, kg 0 accumulates ----
    if (kg > 0) {
        const int widx = (kg - 1) * 2 + rg;
        #pragma unroll
        for (int reg = 0; reg < 4; ++reg) {
            const int rr = q * 4 + reg;
            sm.fin.red[widx][rr][ 0 + r] = acc0[reg];
            sm.fin.red[widx][rr][16 + r] = acc1[reg];
            sm.fin.red[widx][rr][32 + r] = acc2[reg];
            sm.fin.red[widx][rr][48 + r] = acc3[reg];
        }
        if (r == 0) {
            #pragma unroll
            for (int reg = 0; reg < 4; ++reg)
                sm.fin.redl[widx][q * 4 + reg] = accl[reg];
        }
    }
    __syncthreads();
    if (kg == 0) {
        #pragma unroll
        for (int kk = 0; kk < 3; ++kk) {
            const int widx = kk * 2 + rg;
            #pragma unroll
            for (int reg = 0; reg < 4; ++reg) {
                const int rr = q * 4 + reg;
                acc0[reg] += sm.fin.red[widx][rr][ 0 + r];
                acc1[reg] += sm.fin.red[widx][rr][16 + r];
                acc2[reg] += sm.fin.red[widx][rr][32 + r];
                acc3[reg] += sm.fin.red[widx][rr][48 + r];
                accl[reg] += sm.fin.redl[widx][rr];
            }
        }
        // ---- write partial numerator + partial denominator (no normalize) ----
        float* hb = Hpart + ((size_t)(half * NH + h) * NN + n0 + rg * 16) * FOUT;
        #pragma unroll
        for (int reg = 0; reg < 4; ++reg) {
            const int rr = q * 4 + reg;
            hb[rr * FOUT +  0 + r] = acc0[reg];
            hb[rr * FOUT + 16 + r] = acc1[reg];
            hb[rr * FOUT + 32 + r] = acc2[reg];
            hb[rr * FOUT + 48 + r] = acc3[reg];
        }
        if (r == 0) {
            #pragma unroll
            for (int reg = 0; reg < 4; ++reg)
                lpart[(size_t)(half * NH + h) * NN + n0 + rg * 16 + q * 4 + reg] = accl[reg];
        }
    }
}

// ---------------- Kernel 3: fused finalize ----------------
// out[n][o] = sum_h (Hpart0+Hpart1 + wd*Hrow) * 0.25/(l0+l1+wd)
__global__ __launch_bounds__(128) void gat_fin(
    const float* __restrict__ Hpart, const float* __restrict__ Hrow,
    const float* __restrict__ lpart, const float* __restrict__ s_g,
    const float* __restrict__ d_g, float* __restrict__ out)
{
    const int i = blockIdx.x * 128 + threadIdx.x;    // 0..65535
    const int n = i >> 4;
    const int o = (i & 15) * 4;

    f32x4 res = {0.f, 0.f, 0.f, 0.f};
    #pragma unroll
    for (int h = 0; h < NH; ++h) {
        const float l = lpart[(size_t)h * NN + n] + lpart[(size_t)(NH + h) * NN + n];
        const float tt = s_g[h * NN + n] + d_g[h * NN + n];
        const float wd = __expf(fmaxf(tt, 0.01f * tt));
        const float inv = 0.25f / (l + wd);
        f32x4 p0 = *(const f32x4*)&Hpart[((size_t)h * NN + n) * FOUT + o];
        f32x4 p1 = *(const f32x4*)&Hpart[((size_t)(NH + h) * NN + n) * FOUT + o];
        f32x4 hr = *(const f32x4*)&Hrow[((size_t)h * NN + n) * FOUT + o];
        res += (p0 + p1 + wd * hr) * inv;
    }
    *(f32x4*)&out[(size_t)n * FOUT + o] = res;
}

extern "C" void kernel_launch(void* const* d_in, const int* in_sizes, int n_in,
                              void* d_out, int out_size, void* d_ws, size_t ws_size,
                              hipStream_t stream) {
    const float* X   = (const float*)d_in[0];
    const int*   A   = (const int*)  d_in[1];
    const float* W   = (const float*)d_in[2];
    const float* b   = (const float*)d_in[3];
    const float* att = (const float*)d_in[4];
    float* out = (float*)d_out;

    char* ws = (char*)d_ws;
    unsigned short* HbfT = (unsigned short*)ws;                    // 2 MB
    size_t off = (size_t)NH * FOUT * NN * 2;
    float* s_buf   = (float*)(ws + off);  off += (size_t)NH * NN * 4;
    float* d_buf   = (float*)(ws + off);  off += (size_t)NH * NN * 4;
    float* es_buf  = (float*)(ws + off);  off += (size_t)NH * NN * 4;
    float* es2_buf = (float*)(ws + off);  off += (size_t)NH * NN * 4;
    float* ed_buf  = (float*)(ws + off);  off += (size_t)NH * NN * 4;
    float* ed2_buf = (float*)(ws + off);  off += (size_t)NH * NN * 4;
    unsigned long long* Abits = (unsigned long long*)(ws + off);
    off += (size_t)NN * 64 * 8;                                         // 2 MB
    float* Hrow   = (float*)(ws + off);
    off += (size_t)NH * NN * FOUT * 4;                                  // 4 MB
    float* Hpart  = (float*)(ws + off);
    off += (size_t)2 * NH * NN * FOUT * 4;                              // 8 MB
    float* lpart  = (float*)(ws + off);
    off += (size_t)2 * NH * NN * 4;                                     // 128 KB

    pack_bits<<<NN, 256, 0, stream>>>(A, Abits);
    gat_prep<<<dim3(128, 4), 256, 0, stream>>>(X, W, b, att, HbfT, Hrow,
                                               s_buf, d_buf,
                                               es_buf, es2_buf, ed_buf, ed2_buf);
    gat_main<<<1024, 512, 0, stream>>>((const unsigned*)Abits, HbfT,
                                       es_buf, es2_buf, ed_buf, ed2_buf,
                                       Hpart, lpart);
    gat_fin<<<512, 128, 0, stream>>>(Hpart, Hrow, lpart, s_buf, d_buf, out);
}